// Round 16
// baseline (304.799 us; speedup 1.0000x reference)
//
#include <hip/hip_runtime.h>

// Problem: B=1, S=4096, D=1024, H=16, hs=64. f32 in/out, f16 MFMA internally.
#define SEQ 4096
#define DM  1024
#define NH  16
#define HS  64
#define LDQK 2048   // Q|K stacked projection buffer row stride

typedef __attribute__((ext_vector_type(8))) _Float16 f16x8;
typedef __attribute__((ext_vector_type(4))) _Float16 f16x4;
typedef __attribute__((ext_vector_type(4))) float    f32x4;

#define MFMA16(a, b, c)  __builtin_amdgcn_mfma_f32_16x16x32_f16((a), (b), (c), 0, 0, 0)
#define MFMAK16(a, b, c) __builtin_amdgcn_mfma_f32_16x16x16f16((a), (b), (c), 0, 0, 0)

// address-space casts for global_load_lds (flat -> AS1/AS3 via addrspacecast)
#define AS1(p) ((const __attribute__((address_space(1))) void*)(p))
#define AS3(p) ((__attribute__((address_space(3))) void*)(p))

// ---------------------------------------------------------------------------
// single cast launch: y=0 -> x (4M elems), y=1 -> 4 weights (1M each).
// wq/wk land stacked in wqkb[2048][1024] so Q,K project as ONE GEMM.
// ---------------------------------------------------------------------------
__global__ __launch_bounds__(256) void cast_all(
    const float* __restrict__ x,
    const float* __restrict__ wq, const float* __restrict__ wk,
    const float* __restrict__ wv, const float* __restrict__ wo,
    _Float16* __restrict__ xb, _Float16* __restrict__ wqkb,
    _Float16* __restrict__ wvb, _Float16* __restrict__ wob)
{
    const float* s; _Float16* d; int i;
    if (blockIdx.y == 0) {
        s = x; d = xb;
        i = blockIdx.x * 1024 + threadIdx.x * 4;
    } else {
        int wsel = blockIdx.x >> 10;       // 0..3
        int bx   = blockIdx.x & 1023;
        switch (wsel) {
            case 0:  s = wq; d = wqkb;               break;
            case 1:  s = wk; d = wqkb + (1u << 20);  break;  // rows 1024..2047
            case 2:  s = wv; d = wvb;                break;
            default: s = wo; d = wob;                break;
        }
        i = bx * 1024 + threadIdx.x * 4;
    }
    float4 v = *reinterpret_cast<const float4*>(s + i);
    f16x4 o = {(_Float16)v.x, (_Float16)v.y, (_Float16)v.z, (_Float16)v.w};
    *reinterpret_cast<f16x4*>(d + i) = o;
}

// ---------------------------------------------------------------------------
// R10-proven GEMM core: single-buffered gload_lds + XOR swizzle, 4 blocks/CU.
// ---------------------------------------------------------------------------
template <int BM, typename OUT_T>
__device__ __forceinline__ void gemm_core(
    const _Float16* __restrict__ A,    // [M][K]
    const _Float16* __restrict__ W,    // [N][K]
    const float*    __restrict__ bias,
    int nbase, int bias_row,
    OUT_T* __restrict__ C,             // [M][N]
    int N, int K, float scale, int m0, int n0,
    _Float16* As_, _Float16* Bs_)      // [BM][64], [128][64]
{
    constexpr int MI = BM / 32;

    const int t    = threadIdx.x;
    const int w    = t >> 6;
    const int lane = t & 63;
    const int q    = lane >> 4;
    const int l    = lane & 15;
    const int wm   = (w & 1) * (BM / 2);
    const int wn   = (w >> 1) * 64;

    const int srow = lane >> 3;
    const int scol = ((lane & 7) ^ (lane >> 3)) * 8;

    f32x4 acc[MI][4];
    #pragma unroll
    for (int i = 0; i < MI; ++i)
        #pragma unroll
        for (int j = 0; j < 4; ++j) acc[i][j] = (f32x4){0.f, 0.f, 0.f, 0.f};

    for (int k0 = 0; k0 < K; k0 += 64) {
        __syncthreads();
        #pragma unroll
        for (int j = 0; j < BM / 32; ++j) {
            int c = w * (BM / 32) + j;
            __builtin_amdgcn_global_load_lds(
                AS1(A + (size_t)(m0 + c * 8 + srow) * K + k0 + scol),
                AS3((char*)As_ + c * 1024), 16, 0, 0);
        }
        #pragma unroll
        for (int j = 0; j < 4; ++j) {
            int c = w * 4 + j;
            __builtin_amdgcn_global_load_lds(
                AS1(W + (size_t)(n0 + c * 8 + srow) * K + k0 + scol),
                AS3((char*)Bs_ + c * 1024), 16, 0, 0);
        }
        __syncthreads();

        #pragma unroll
        for (int ks = 0; ks < 64; ks += 32) {
            f16x8 af[MI], bf[4];
            #pragma unroll
            for (int i = 0; i < MI; ++i) {
                int r = wm + i * 16 + l;
                af[i] = *reinterpret_cast<const f16x8*>(
                    (const char*)As_ + r * 128 +
                    ((((ks >> 3) + q) ^ (l & 7)) << 4));
            }
            #pragma unroll
            for (int j = 0; j < 4; ++j) {
                int r = wn + j * 16 + l;
                bf[j] = *reinterpret_cast<const f16x8*>(
                    (const char*)Bs_ + r * 128 +
                    ((((ks >> 3) + q) ^ (l & 7)) << 4));
            }
            #pragma unroll
            for (int i = 0; i < MI; ++i)
                #pragma unroll
                for (int j = 0; j < 4; ++j)
                    acc[i][j] = MFMA16(af[i], bf[j], acc[i][j]);
        }
    }

    #pragma unroll
    for (int i = 0; i < MI; ++i) {
        #pragma unroll
        for (int j = 0; j < 4; ++j) {
            int gnb = n0 + wn + j * 16 + l;
            float bc2 = bias_row ? 0.f : bias[gnb - nbase];
            #pragma unroll
            for (int r = 0; r < 4; ++r) {
                int gm = m0 + wm + i * 16 + q * 4 + r;
                float bb = bias_row ? bias[gm] : bc2;
                C[(size_t)gm * N + gnb] = (OUT_T)((acc[i][j][r] + bb) * scale);
            }
        }
    }
}

// Fused QK-proj + V-proj, 768 blocks, BM=128, 32 KB LDS -> 4 blocks/CU.
__global__ __launch_bounds__(256, 4) void gemm_qkv(
    const _Float16* __restrict__ xb, const _Float16* __restrict__ wqkb,
    const _Float16* __restrict__ wvb,
    const float* __restrict__ bq, const float* __restrict__ bk,
    const float* __restrict__ bv,
    _Float16* __restrict__ QKb, _Float16* __restrict__ Vtb)
{
    __shared__ _Float16 As[128][64];
    __shared__ _Float16 Bs[128][64];

    const int bid = (blockIdx.x & 7) * 96 + (blockIdx.x >> 3);
    if (bid < 512) {
        const int n0 = (bid & 15) * 128, m0 = (bid >> 4) * 128;
        const float* bias = (n0 < 1024) ? bq : bk;
        const int   nbase = (n0 < 1024) ? 0 : 1024;
        const float scale = (n0 < 1024) ? 0.18033688011112042f : 1.0f;
        gemm_core<128, _Float16>(xb, wqkb, bias, nbase, 0, QKb,
                                 2048, 1024, scale, m0, n0,
                                 &As[0][0], &Bs[0][0]);
    } else {
        const int v = bid - 512;
        const int n0 = (v & 31) * 128, m0 = (v >> 5) * 128;
        gemm_core<128, _Float16>(wvb, xb, bv, 0, 1, Vtb,
                                 4096, 1024, 1.0f, m0, n0,
                                 &As[0][0], &Bs[0][0]);
    }
}

// O-projection: out = attn@wo^T + bo (f32 out). BM=64, 512 blocks, 24 KB.
__global__ __launch_bounds__(256, 4) void gemm_o(
    const _Float16* __restrict__ Ab, const _Float16* __restrict__ wob,
    const float* __restrict__ bo, float* __restrict__ out)
{
    __shared__ _Float16 As[64][64];
    __shared__ _Float16 Bs[128][64];
    const int n0 = blockIdx.x * 128, m0 = blockIdx.y * 64;
    gemm_core<64, float>(Ab, wob, bo, 0, 0, out, 1024, 1024, 1.0f, m0, n0,
                         &As[0][0], &Bs[0][0]);
}

// ---------------------------------------------------------------------------
// R15 attn (k-split waves + swapped QK + in-register P), R16 change: bump
// __launch_bounds__ (256,3) -> (256,4). Measured VGPR=84 <= 128 cap at
// 4 waves/SIMD (m69 step), LDS 27.6 KB allows 5 blocks/CU, grid 1024 = 4/CU.
// R15 profile: MfmaUtil 33%, VALUBusy 39%, Occupancy 21% (3 blocks/CU) —
// latency-bound; 4th resident block converts directly to issue overlap.
//
//  * wave w owns k-slice [w*16, w*16+16) of each 64-k tile, ALL 64 q-rows.
//  * QK swapped: mfma(A=K-frag, B=Q-frag) -> acc = S^T tile (col=q, row=k).
//    acc layout (lane: q=l&15, k=(l>>4)*4+r) IS the A-fragment layout of
//    mfma_f32_16x16x16f16 -> P feeds PV directly from registers after exp2.
//  * PV: 16x16x16 MFMA, K=16; B=V from Vs (V^T [d][k]) as f16x4.
//  * partials (full 64q x 64d per wave) + denominators combined in a
//    4-round LDS-exchange epilogue (overlays Qs/Ks/Vs).
// Causal mask (kt==qb): keep iff w*16+g*4+r <= qt*16+lo.
// ---------------------------------------------------------------------------
#define APAD 72

__global__ __launch_bounds__(256, 4) void attn_mfma(
    const _Float16* __restrict__ Qg,  // [SEQ][LDQK] cols 0..1023 (pre-scaled)
    const _Float16* __restrict__ Kg,  // [SEQ][LDQK] (base already +1024)
    const _Float16* __restrict__ Vt,  // [DM][SEQ]
    _Float16* __restrict__ O)         // [SEQ][DM]
{
    __shared__ __align__(16) char smem[27648];
    _Float16 (*Qs)[APAD] = reinterpret_cast<_Float16(*)[APAD]>(smem);          // 9216 B
    _Float16 (*Ks)[APAD] = reinterpret_cast<_Float16(*)[APAD]>(smem + 9216);   // rows=k
    _Float16 (*Vs)[APAD] = reinterpret_cast<_Float16(*)[APAD]>(smem + 18432);  // rows=d (V^T)
    // epilogue overlays: Xl on Qs (4 KB) + Xd (256 B); Xo on Ks+Vs (12 KB)
    float* Xl = reinterpret_cast<float*>(smem);
    float* Xd = reinterpret_cast<float*>(smem + 4096);
    float* Xo = reinterpret_cast<float*>(smem + 9216);

    const int t    = threadIdx.x;
    const int h    = blockIdx.x;
    const int by   = blockIdx.y;      // 0..63
    const int qb   = (by < 32) ? by : 95 - by;   // balanced q-tile index
    const int w    = t >> 6;          // wave 0..3 = k-slice owner
    const int lane = t & 63;
    const int lo   = lane & 15;
    const int g    = lane >> 4;       // 0..3
    const int sr   = t >> 3;          // 0..31 staging row
    const int sc   = (t & 7) * 8;     // staging col (f16)

    // stage Q (64 rows x 64 cols)
    *reinterpret_cast<uint4*>(&Qs[sr][sc]) =
        *reinterpret_cast<const uint4*>(Qg + (size_t)(qb * 64 + sr) * LDQK + h * 64 + sc);
    *reinterpret_cast<uint4*>(&Qs[sr + 32][sc]) =
        *reinterpret_cast<const uint4*>(Qg + (size_t)(qb * 64 + sr + 32) * LDQK + h * 64 + sc);

    // prefetch kt=0 K/V into registers
    uint4 kr0 = *reinterpret_cast<const uint4*>(Kg + (size_t)(sr) * LDQK + h * 64 + sc);
    uint4 kr1 = *reinterpret_cast<const uint4*>(Kg + (size_t)(sr + 32) * LDQK + h * 64 + sc);
    uint4 vr0 = *reinterpret_cast<const uint4*>(Vt + (size_t)(h * 64 + sr) * SEQ + sc);
    uint4 vr1 = *reinterpret_cast<const uint4*>(Vt + (size_t)(h * 64 + sr + 32) * SEQ + sc);

    float l_acc[4] = {0.f, 0.f, 0.f, 0.f};     // per q-tile partial denom
    f32x4 oacc[4][4];                          // [qt][dt] full 64x64 partial
    #pragma unroll
    for (int qt = 0; qt < 4; ++qt)
        #pragma unroll
        for (int dt = 0; dt < 4; ++dt) oacc[qt][dt] = (f32x4){0.f, 0.f, 0.f, 0.f};

    __syncthreads();   // Qs visible

    // hoist Q B-frags: bq[qt][half], lane holds Q[q=qt*16+lo][hs=half*32+g*8+e]
    f16x8 bq[4][2];
    #pragma unroll
    for (int qt = 0; qt < 4; ++qt) {
        bq[qt][0] = *reinterpret_cast<const f16x8*>(&Qs[qt * 16 + lo][g * 8]);
        bq[qt][1] = *reinterpret_cast<const f16x8*>(&Qs[qt * 16 + lo][32 + g * 8]);
    }

    for (int kt = 0; kt <= qb; ++kt) {
        __syncthreads();   // prev iter's Ks/Vs reads done
        *reinterpret_cast<uint4*>(&Ks[sr][sc])      = kr0;
        *reinterpret_cast<uint4*>(&Ks[sr + 32][sc]) = kr1;
        *reinterpret_cast<uint4*>(&Vs[sr][sc])      = vr0;
        *reinterpret_cast<uint4*>(&Vs[sr + 32][sc]) = vr1;
        if (kt < qb) {   // issue kt+1 global loads
            kr0 = *reinterpret_cast<const uint4*>(
                Kg + (size_t)((kt + 1) * 64 + sr) * LDQK + h * 64 + sc);
            kr1 = *reinterpret_cast<const uint4*>(
                Kg + (size_t)((kt + 1) * 64 + sr + 32) * LDQK + h * 64 + sc);
            vr0 = *reinterpret_cast<const uint4*>(
                Vt + (size_t)(h * 64 + sr) * SEQ + (kt + 1) * 64 + sc);
            vr1 = *reinterpret_cast<const uint4*>(
                Vt + (size_t)(h * 64 + sr + 32) * SEQ + (kt + 1) * 64 + sc);
        }
        __syncthreads();   // LDS writes visible

        // K A-frags for this wave's k-slice: A[k=w*16+lo][hs=half*32+g*8+e]
        f16x8 ak0 = *reinterpret_cast<const f16x8*>(&Ks[w * 16 + lo][g * 8]);
        f16x8 ak1 = *reinterpret_cast<const f16x8*>(&Ks[w * 16 + lo][32 + g * 8]);
        // V B-frags: B[k=g*4+e (slice-rel)][d=dt*16+lo] from Vs[d][k]
        f16x4 bv[4];
        #pragma unroll
        for (int dt = 0; dt < 4; ++dt)
            bv[dt] = *reinterpret_cast<const f16x4*>(&Vs[dt * 16 + lo][w * 16 + g * 4]);

        const bool diag = (kt == qb);

        __builtin_amdgcn_s_setprio(1);
        #pragma unroll
        for (int qt = 0; qt < 4; ++qt) {
            // S^T tile: z[r] = S'[q=qt*16+lo][k = kt*64 + w*16 + g*4 + r]
            f32x4 z = (f32x4){0.f, 0.f, 0.f, 0.f};
            z = MFMA16(ak0, bq[qt][0], z);
            z = MFMA16(ak1, bq[qt][1], z);

            float p0 = z[0], p1 = z[1], p2 = z[2], p3 = z[3];
            if (diag) {
                const int qg = qt * 16 + lo;
                const int kg = w * 16 + g * 4;
                p0 = (kg + 0 <= qg) ? p0 : -1e30f;
                p1 = (kg + 1 <= qg) ? p1 : -1e30f;
                p2 = (kg + 2 <= qg) ? p2 : -1e30f;
                p3 = (kg + 3 <= qg) ? p3 : -1e30f;
            }
            p0 = __builtin_amdgcn_exp2f(p0 - 4.f);
            p1 = __builtin_amdgcn_exp2f(p1 - 4.f);
            p2 = __builtin_amdgcn_exp2f(p2 - 4.f);
            p3 = __builtin_amdgcn_exp2f(p3 - 4.f);
            l_acc[qt] += (p0 + p1) + (p2 + p3);

            // a IS the PV A-fragment: A[q=lo][k=g*4+r] (in registers)
            f16x4 a = {(_Float16)p0, (_Float16)p1, (_Float16)p2, (_Float16)p3};
            #pragma unroll
            for (int dt = 0; dt < 4; ++dt)
                oacc[qt][dt] = MFMAK16(a, bv[dt], oacc[qt][dt]);
        }
        __builtin_amdgcn_s_setprio(0);
    }

    // ---- epilogue: combine wave partials, normalize, store ----
    __syncthreads();   // all loop LDS reads done before overlay writes

    // 1) denominators: write per-lane partials, reduce per q-row
    #pragma unroll
    for (int qt = 0; qt < 4; ++qt)
        Xl[((w * 4 + qt) * 4 + g) * 16 + lo] = l_acc[qt];
    __syncthreads();
    if (t < 64) {
        float s = 0.f;
        #pragma unroll
        for (int v = 0; v < 4; ++v)
            #pragma unroll
            for (int gg = 0; gg < 4; ++gg)
                s += Xl[((v * 4 + (t >> 4)) * 4 + gg) * 16 + (t & 15)];
        Xd[t] = 1.f / s;
    }
    __syncthreads();

    // 2) O partial sum across waves, one q-tile per round; owner = wave qt
    for (int qt = 0; qt < 4; ++qt) {
        if (w != qt) {
            int widx = w - (w > qt);
            #pragma unroll
            for (int dt = 0; dt < 4; ++dt)
                *reinterpret_cast<f32x4*>(Xo + ((widx * 4 + dt) * 64 + lane) * 4) =
                    oacc[qt][dt];
        }
        __syncthreads();
        if (w == qt) {
            float inv[4];
            #pragma unroll
            for (int r = 0; r < 4; ++r) inv[r] = Xd[qt * 16 + g * 4 + r];
            #pragma unroll
            for (int dt = 0; dt < 4; ++dt) {
                f32x4 s = oacc[qt][dt];
                #pragma unroll
                for (int widx = 0; widx < 3; ++widx)
                    s += *reinterpret_cast<const f32x4*>(
                        Xo + ((widx * 4 + dt) * 64 + lane) * 4);
                #pragma unroll
                for (int r = 0; r < 4; ++r)
                    O[(size_t)(qb * 64 + qt * 16 + g * 4 + r) * DM + h * 64 +
                      dt * 16 + lo] = (_Float16)(s[r] * inv[r]);
            }
        }
        __syncthreads();
    }
}

// ---------------------------------------------------------------------------
extern "C" void kernel_launch(void* const* d_in, const int* in_sizes, int n_in,
                              void* d_out, int out_size, void* d_ws, size_t ws_size,
                              hipStream_t stream)
{
    const float* x  = (const float*)d_in[0];
    const float* wq = (const float*)d_in[1];
    const float* bq = (const float*)d_in[2];
    const float* wk = (const float*)d_in[3];
    const float* bk = (const float*)d_in[4];
    const float* wv = (const float*)d_in[5];
    const float* bv = (const float*)d_in[6];
    const float* wo = (const float*)d_in[7];
    const float* bo = (const float*)d_in[8];
    float* out = (float*)d_out;

    char* ws = (char*)d_ws;
    _Float16* xb   = (_Float16*)(ws);                    // 8 MB
    _Float16* wqkb = (_Float16*)(ws + (8ull  << 20));    // 4 MB [wq;wk] stacked
    _Float16* wvb  = (_Float16*)(ws + (12ull << 20));    // 2 MB
    _Float16* wob  = (_Float16*)(ws + (14ull << 20));    // 2 MB
    _Float16* QKb  = (_Float16*)(ws + (16ull << 20));    // 16 MB [SEQ][2048]: Q|K
    _Float16* Vtb  = (_Float16*)(ws + (32ull << 20));    // 8 MB V^T [DM][SEQ]
    _Float16* Ab   = (_Float16*)(ws + (40ull << 20));    // 8 MB attn out

    // one cast launch: x + all 4 weights (wq/wk stacked into wqkb)
    cast_all<<<dim3(SEQ * DM / 1024, 2), dim3(256), 0, stream>>>(
        x, wq, wk, wv, wo, xb, wqkb, wvb, wob);

    // fused QK + V projections: 768 blocks, 32 KB LDS -> 4 blocks/CU
    gemm_qkv<<<dim3(768), dim3(256), 0, stream>>>(
        xb, wqkb, wvb, bq, bk, bv, QKb, Vtb);

    // attn: 1024 blocks, 27.6 KB LDS, (256,4) -> 4 blocks/CU
    attn_mfma<<<dim3(NH, 64), dim3(256), 0, stream>>>(QKb, QKb + 1024, Vtb, Ab);

    // out = attn@wo^T + bo (f32 out), BM=64 -> 512 blocks, 24 KB LDS
    gemm_o<<<dim3(DM / 128, SEQ / 64), dim3(256), 0, stream>>>(
        Ab, wob, bo, out);
}

// Round 17
// 204.355 us; speedup vs baseline: 1.4915x; 1.4915x over previous
//
#include <hip/hip_runtime.h>

// Problem: B=1, S=4096, D=1024, H=16, hs=64. f32 in/out, f16 MFMA internally.
// R17 = R15 verbatim (session best, 195.2 us). R16's (256,4) bump spilled:
// gfx950 unified VGPR/AGPR file — oacc's 64 AGPRs count against the budget,
// so true usage ~148 regs > 128 cap at 4 waves/SIMD (VGPR_Count 84->64,
// WRITE_SIZE 8->47 MB scratch traffic, attn 68->173 us). (256,3) is correct.
#define SEQ 4096
#define DM  1024
#define NH  16
#define HS  64
#define LDQK 2048   // Q|K stacked projection buffer row stride

typedef __attribute__((ext_vector_type(8))) _Float16 f16x8;
typedef __attribute__((ext_vector_type(4))) _Float16 f16x4;
typedef __attribute__((ext_vector_type(4))) float    f32x4;

#define MFMA16(a, b, c)  __builtin_amdgcn_mfma_f32_16x16x32_f16((a), (b), (c), 0, 0, 0)
#define MFMAK16(a, b, c) __builtin_amdgcn_mfma_f32_16x16x16f16((a), (b), (c), 0, 0, 0)

// address-space casts for global_load_lds (flat -> AS1/AS3 via addrspacecast)
#define AS1(p) ((const __attribute__((address_space(1))) void*)(p))
#define AS3(p) ((__attribute__((address_space(3))) void*)(p))

// ---------------------------------------------------------------------------
// single cast launch: y=0 -> x (4M elems), y=1 -> 4 weights (1M each).
// wq/wk land stacked in wqkb[2048][1024] so Q,K project as ONE GEMM.
// ---------------------------------------------------------------------------
__global__ __launch_bounds__(256) void cast_all(
    const float* __restrict__ x,
    const float* __restrict__ wq, const float* __restrict__ wk,
    const float* __restrict__ wv, const float* __restrict__ wo,
    _Float16* __restrict__ xb, _Float16* __restrict__ wqkb,
    _Float16* __restrict__ wvb, _Float16* __restrict__ wob)
{
    const float* s; _Float16* d; int i;
    if (blockIdx.y == 0) {
        s = x; d = xb;
        i = blockIdx.x * 1024 + threadIdx.x * 4;
    } else {
        int wsel = blockIdx.x >> 10;       // 0..3
        int bx   = blockIdx.x & 1023;
        switch (wsel) {
            case 0:  s = wq; d = wqkb;               break;
            case 1:  s = wk; d = wqkb + (1u << 20);  break;  // rows 1024..2047
            case 2:  s = wv; d = wvb;                break;
            default: s = wo; d = wob;                break;
        }
        i = bx * 1024 + threadIdx.x * 4;
    }
    float4 v = *reinterpret_cast<const float4*>(s + i);
    f16x4 o = {(_Float16)v.x, (_Float16)v.y, (_Float16)v.z, (_Float16)v.w};
    *reinterpret_cast<f16x4*>(d + i) = o;
}

// ---------------------------------------------------------------------------
// R10-proven GEMM core: single-buffered gload_lds + XOR swizzle, 4 blocks/CU.
// ---------------------------------------------------------------------------
template <int BM, typename OUT_T>
__device__ __forceinline__ void gemm_core(
    const _Float16* __restrict__ A,    // [M][K]
    const _Float16* __restrict__ W,    // [N][K]
    const float*    __restrict__ bias,
    int nbase, int bias_row,
    OUT_T* __restrict__ C,             // [M][N]
    int N, int K, float scale, int m0, int n0,
    _Float16* As_, _Float16* Bs_)      // [BM][64], [128][64]
{
    constexpr int MI = BM / 32;

    const int t    = threadIdx.x;
    const int w    = t >> 6;
    const int lane = t & 63;
    const int q    = lane >> 4;
    const int l    = lane & 15;
    const int wm   = (w & 1) * (BM / 2);
    const int wn   = (w >> 1) * 64;

    const int srow = lane >> 3;
    const int scol = ((lane & 7) ^ (lane >> 3)) * 8;

    f32x4 acc[MI][4];
    #pragma unroll
    for (int i = 0; i < MI; ++i)
        #pragma unroll
        for (int j = 0; j < 4; ++j) acc[i][j] = (f32x4){0.f, 0.f, 0.f, 0.f};

    for (int k0 = 0; k0 < K; k0 += 64) {
        __syncthreads();
        #pragma unroll
        for (int j = 0; j < BM / 32; ++j) {
            int c = w * (BM / 32) + j;
            __builtin_amdgcn_global_load_lds(
                AS1(A + (size_t)(m0 + c * 8 + srow) * K + k0 + scol),
                AS3((char*)As_ + c * 1024), 16, 0, 0);
        }
        #pragma unroll
        for (int j = 0; j < 4; ++j) {
            int c = w * 4 + j;
            __builtin_amdgcn_global_load_lds(
                AS1(W + (size_t)(n0 + c * 8 + srow) * K + k0 + scol),
                AS3((char*)Bs_ + c * 1024), 16, 0, 0);
        }
        __syncthreads();

        #pragma unroll
        for (int ks = 0; ks < 64; ks += 32) {
            f16x8 af[MI], bf[4];
            #pragma unroll
            for (int i = 0; i < MI; ++i) {
                int r = wm + i * 16 + l;
                af[i] = *reinterpret_cast<const f16x8*>(
                    (const char*)As_ + r * 128 +
                    ((((ks >> 3) + q) ^ (l & 7)) << 4));
            }
            #pragma unroll
            for (int j = 0; j < 4; ++j) {
                int r = wn + j * 16 + l;
                bf[j] = *reinterpret_cast<const f16x8*>(
                    (const char*)Bs_ + r * 128 +
                    ((((ks >> 3) + q) ^ (l & 7)) << 4));
            }
            #pragma unroll
            for (int i = 0; i < MI; ++i)
                #pragma unroll
                for (int j = 0; j < 4; ++j)
                    acc[i][j] = MFMA16(af[i], bf[j], acc[i][j]);
        }
    }

    #pragma unroll
    for (int i = 0; i < MI; ++i) {
        #pragma unroll
        for (int j = 0; j < 4; ++j) {
            int gnb = n0 + wn + j * 16 + l;
            float bc2 = bias_row ? 0.f : bias[gnb - nbase];
            #pragma unroll
            for (int r = 0; r < 4; ++r) {
                int gm = m0 + wm + i * 16 + q * 4 + r;
                float bb = bias_row ? bias[gm] : bc2;
                C[(size_t)gm * N + gnb] = (OUT_T)((acc[i][j][r] + bb) * scale);
            }
        }
    }
}

// Fused QK-proj + V-proj, 768 blocks, BM=128, 32 KB LDS -> 4 blocks/CU.
__global__ __launch_bounds__(256, 4) void gemm_qkv(
    const _Float16* __restrict__ xb, const _Float16* __restrict__ wqkb,
    const _Float16* __restrict__ wvb,
    const float* __restrict__ bq, const float* __restrict__ bk,
    const float* __restrict__ bv,
    _Float16* __restrict__ QKb, _Float16* __restrict__ Vtb)
{
    __shared__ _Float16 As[128][64];
    __shared__ _Float16 Bs[128][64];

    const int bid = (blockIdx.x & 7) * 96 + (blockIdx.x >> 3);
    if (bid < 512) {
        const int n0 = (bid & 15) * 128, m0 = (bid >> 4) * 128;
        const float* bias = (n0 < 1024) ? bq : bk;
        const int   nbase = (n0 < 1024) ? 0 : 1024;
        const float scale = (n0 < 1024) ? 0.18033688011112042f : 1.0f;
        gemm_core<128, _Float16>(xb, wqkb, bias, nbase, 0, QKb,
                                 2048, 1024, scale, m0, n0,
                                 &As[0][0], &Bs[0][0]);
    } else {
        const int v = bid - 512;
        const int n0 = (v & 31) * 128, m0 = (v >> 5) * 128;
        gemm_core<128, _Float16>(wvb, xb, bv, 0, 1, Vtb,
                                 4096, 1024, 1.0f, m0, n0,
                                 &As[0][0], &Bs[0][0]);
    }
}

// O-projection: out = attn@wo^T + bo (f32 out). BM=64, 512 blocks, 24 KB.
__global__ __launch_bounds__(256, 4) void gemm_o(
    const _Float16* __restrict__ Ab, const _Float16* __restrict__ wob,
    const float* __restrict__ bo, float* __restrict__ out)
{
    __shared__ _Float16 As[64][64];
    __shared__ _Float16 Bs[128][64];
    const int n0 = blockIdx.x * 128, m0 = blockIdx.y * 64;
    gemm_core<64, float>(Ab, wob, bo, 0, 0, out, 1024, 1024, 1.0f, m0, n0,
                         &As[0][0], &Bs[0][0]);
}

// ---------------------------------------------------------------------------
// R15 attn: k-split waves + SWAPPED QK + in-register P (no P LDS round-trip).
// Measured 68.4 us (MfmaUtil 33%, bank-conflicts 1.2M vs 9.6M in R3 form).
//  * wave w owns k-slice [w*16, w*16+16) of each 64-k tile, ALL 64 q-rows.
//  * QK swapped: mfma(A=K-frag, B=Q-frag) -> acc = S^T tile (col=q, row=k).
//    acc layout (lane: q=l&15, k=(l>>4)*4+r) IS the A-fragment layout of
//    mfma_f32_16x16x16f16 -> P feeds PV directly from registers after exp2.
//  * PV: 16x16x16 MFMA, K=16; B=V from Vs (V^T [d][k]) as f16x4.
//  * partials (full 64q x 64d per wave, 64 AGPRs) + denominators combined
//    in a 4-round LDS-exchange epilogue (overlays Qs/Ks/Vs).
// Causal mask (kt==qb): keep iff w*16+g*4+r <= qt*16+lo.
// (256,3): unified VGPR+AGPR ~148 regs -> fits 168-cap at 3 waves/SIMD only.
// ---------------------------------------------------------------------------
#define APAD 72

__global__ __launch_bounds__(256, 3) void attn_mfma(
    const _Float16* __restrict__ Qg,  // [SEQ][LDQK] cols 0..1023 (pre-scaled)
    const _Float16* __restrict__ Kg,  // [SEQ][LDQK] (base already +1024)
    const _Float16* __restrict__ Vt,  // [DM][SEQ]
    _Float16* __restrict__ O)         // [SEQ][DM]
{
    __shared__ __align__(16) char smem[27648];
    _Float16 (*Qs)[APAD] = reinterpret_cast<_Float16(*)[APAD]>(smem);          // 9216 B
    _Float16 (*Ks)[APAD] = reinterpret_cast<_Float16(*)[APAD]>(smem + 9216);   // rows=k
    _Float16 (*Vs)[APAD] = reinterpret_cast<_Float16(*)[APAD]>(smem + 18432);  // rows=d (V^T)
    // epilogue overlays: Xl on Qs (4 KB) + Xd (256 B); Xo on Ks+Vs (12 KB)
    float* Xl = reinterpret_cast<float*>(smem);
    float* Xd = reinterpret_cast<float*>(smem + 4096);
    float* Xo = reinterpret_cast<float*>(smem + 9216);

    const int t    = threadIdx.x;
    const int h    = blockIdx.x;
    const int by   = blockIdx.y;      // 0..63
    const int qb   = (by < 32) ? by : 95 - by;   // balanced q-tile index
    const int w    = t >> 6;          // wave 0..3 = k-slice owner
    const int lane = t & 63;
    const int lo   = lane & 15;
    const int g    = lane >> 4;       // 0..3
    const int sr   = t >> 3;          // 0..31 staging row
    const int sc   = (t & 7) * 8;     // staging col (f16)

    // stage Q (64 rows x 64 cols)
    *reinterpret_cast<uint4*>(&Qs[sr][sc]) =
        *reinterpret_cast<const uint4*>(Qg + (size_t)(qb * 64 + sr) * LDQK + h * 64 + sc);
    *reinterpret_cast<uint4*>(&Qs[sr + 32][sc]) =
        *reinterpret_cast<const uint4*>(Qg + (size_t)(qb * 64 + sr + 32) * LDQK + h * 64 + sc);

    // prefetch kt=0 K/V into registers
    uint4 kr0 = *reinterpret_cast<const uint4*>(Kg + (size_t)(sr) * LDQK + h * 64 + sc);
    uint4 kr1 = *reinterpret_cast<const uint4*>(Kg + (size_t)(sr + 32) * LDQK + h * 64 + sc);
    uint4 vr0 = *reinterpret_cast<const uint4*>(Vt + (size_t)(h * 64 + sr) * SEQ + sc);
    uint4 vr1 = *reinterpret_cast<const uint4*>(Vt + (size_t)(h * 64 + sr + 32) * SEQ + sc);

    float l_acc[4] = {0.f, 0.f, 0.f, 0.f};     // per q-tile partial denom
    f32x4 oacc[4][4];                          // [qt][dt] full 64x64 partial
    #pragma unroll
    for (int qt = 0; qt < 4; ++qt)
        #pragma unroll
        for (int dt = 0; dt < 4; ++dt) oacc[qt][dt] = (f32x4){0.f, 0.f, 0.f, 0.f};

    __syncthreads();   // Qs visible

    // hoist Q B-frags: bq[qt][half], lane holds Q[q=qt*16+lo][hs=half*32+g*8+e]
    f16x8 bq[4][2];
    #pragma unroll
    for (int qt = 0; qt < 4; ++qt) {
        bq[qt][0] = *reinterpret_cast<const f16x8*>(&Qs[qt * 16 + lo][g * 8]);
        bq[qt][1] = *reinterpret_cast<const f16x8*>(&Qs[qt * 16 + lo][32 + g * 8]);
    }

    for (int kt = 0; kt <= qb; ++kt) {
        __syncthreads();   // prev iter's Ks/Vs reads done
        *reinterpret_cast<uint4*>(&Ks[sr][sc])      = kr0;
        *reinterpret_cast<uint4*>(&Ks[sr + 32][sc]) = kr1;
        *reinterpret_cast<uint4*>(&Vs[sr][sc])      = vr0;
        *reinterpret_cast<uint4*>(&Vs[sr + 32][sc]) = vr1;
        if (kt < qb) {   // issue kt+1 global loads
            kr0 = *reinterpret_cast<const uint4*>(
                Kg + (size_t)((kt + 1) * 64 + sr) * LDQK + h * 64 + sc);
            kr1 = *reinterpret_cast<const uint4*>(
                Kg + (size_t)((kt + 1) * 64 + sr + 32) * LDQK + h * 64 + sc);
            vr0 = *reinterpret_cast<const uint4*>(
                Vt + (size_t)(h * 64 + sr) * SEQ + (kt + 1) * 64 + sc);
            vr1 = *reinterpret_cast<const uint4*>(
                Vt + (size_t)(h * 64 + sr + 32) * SEQ + (kt + 1) * 64 + sc);
        }
        __syncthreads();   // LDS writes visible

        // K A-frags for this wave's k-slice: A[k=w*16+lo][hs=half*32+g*8+e]
        f16x8 ak0 = *reinterpret_cast<const f16x8*>(&Ks[w * 16 + lo][g * 8]);
        f16x8 ak1 = *reinterpret_cast<const f16x8*>(&Ks[w * 16 + lo][32 + g * 8]);
        // V B-frags: B[k=g*4+e (slice-rel)][d=dt*16+lo] from Vs[d][k]
        f16x4 bv[4];
        #pragma unroll
        for (int dt = 0; dt < 4; ++dt)
            bv[dt] = *reinterpret_cast<const f16x4*>(&Vs[dt * 16 + lo][w * 16 + g * 4]);

        const bool diag = (kt == qb);

        __builtin_amdgcn_s_setprio(1);
        #pragma unroll
        for (int qt = 0; qt < 4; ++qt) {
            // S^T tile: z[r] = S'[q=qt*16+lo][k = kt*64 + w*16 + g*4 + r]
            f32x4 z = (f32x4){0.f, 0.f, 0.f, 0.f};
            z = MFMA16(ak0, bq[qt][0], z);
            z = MFMA16(ak1, bq[qt][1], z);

            float p0 = z[0], p1 = z[1], p2 = z[2], p3 = z[3];
            if (diag) {
                const int qg = qt * 16 + lo;
                const int kg = w * 16 + g * 4;
                p0 = (kg + 0 <= qg) ? p0 : -1e30f;
                p1 = (kg + 1 <= qg) ? p1 : -1e30f;
                p2 = (kg + 2 <= qg) ? p2 : -1e30f;
                p3 = (kg + 3 <= qg) ? p3 : -1e30f;
            }
            p0 = __builtin_amdgcn_exp2f(p0 - 4.f);
            p1 = __builtin_amdgcn_exp2f(p1 - 4.f);
            p2 = __builtin_amdgcn_exp2f(p2 - 4.f);
            p3 = __builtin_amdgcn_exp2f(p3 - 4.f);
            l_acc[qt] += (p0 + p1) + (p2 + p3);

            // a IS the PV A-fragment: A[q=lo][k=g*4+r] (in registers)
            f16x4 a = {(_Float16)p0, (_Float16)p1, (_Float16)p2, (_Float16)p3};
            #pragma unroll
            for (int dt = 0; dt < 4; ++dt)
                oacc[qt][dt] = MFMAK16(a, bv[dt], oacc[qt][dt]);
        }
        __builtin_amdgcn_s_setprio(0);
    }

    // ---- epilogue: combine wave partials, normalize, store ----
    __syncthreads();   // all loop LDS reads done before overlay writes

    // 1) denominators: write per-lane partials, reduce per q-row
    #pragma unroll
    for (int qt = 0; qt < 4; ++qt)
        Xl[((w * 4 + qt) * 4 + g) * 16 + lo] = l_acc[qt];
    __syncthreads();
    if (t < 64) {
        float s = 0.f;
        #pragma unroll
        for (int v = 0; v < 4; ++v)
            #pragma unroll
            for (int gg = 0; gg < 4; ++gg)
                s += Xl[((v * 4 + (t >> 4)) * 4 + gg) * 16 + (t & 15)];
        Xd[t] = 1.f / s;
    }
    __syncthreads();

    // 2) O partial sum across waves, one q-tile per round; owner = wave qt
    for (int qt = 0; qt < 4; ++qt) {
        if (w != qt) {
            int widx = w - (w > qt);
            #pragma unroll
            for (int dt = 0; dt < 4; ++dt)
                *reinterpret_cast<f32x4*>(Xo + ((widx * 4 + dt) * 64 + lane) * 4) =
                    oacc[qt][dt];
        }
        __syncthreads();
        if (w == qt) {
            float inv[4];
            #pragma unroll
            for (int r = 0; r < 4; ++r) inv[r] = Xd[qt * 16 + g * 4 + r];
            #pragma unroll
            for (int dt = 0; dt < 4; ++dt) {
                f32x4 s = oacc[qt][dt];
                #pragma unroll
                for (int widx = 0; widx < 3; ++widx)
                    s += *reinterpret_cast<const f32x4*>(
                        Xo + ((widx * 4 + dt) * 64 + lane) * 4);
                #pragma unroll
                for (int r = 0; r < 4; ++r)
                    O[(size_t)(qb * 64 + qt * 16 + g * 4 + r) * DM + h * 64 +
                      dt * 16 + lo] = (_Float16)(s[r] * inv[r]);
            }
        }
        __syncthreads();
    }
}

// ---------------------------------------------------------------------------
extern "C" void kernel_launch(void* const* d_in, const int* in_sizes, int n_in,
                              void* d_out, int out_size, void* d_ws, size_t ws_size,
                              hipStream_t stream)
{
    const float* x  = (const float*)d_in[0];
    const float* wq = (const float*)d_in[1];
    const float* bq = (const float*)d_in[2];
    const float* wk = (const float*)d_in[3];
    const float* bk = (const float*)d_in[4];
    const float* wv = (const float*)d_in[5];
    const float* bv = (const float*)d_in[6];
    const float* wo = (const float*)d_in[7];
    const float* bo = (const float*)d_in[8];
    float* out = (float*)d_out;

    char* ws = (char*)d_ws;
    _Float16* xb   = (_Float16*)(ws);                    // 8 MB
    _Float16* wqkb = (_Float16*)(ws + (8ull  << 20));    // 4 MB [wq;wk] stacked
    _Float16* wvb  = (_Float16*)(ws + (12ull << 20));    // 2 MB
    _Float16* wob  = (_Float16*)(ws + (14ull << 20));    // 2 MB
    _Float16* QKb  = (_Float16*)(ws + (16ull << 20));    // 16 MB [SEQ][2048]: Q|K
    _Float16* Vtb  = (_Float16*)(ws + (32ull << 20));    // 8 MB V^T [DM][SEQ]
    _Float16* Ab   = (_Float16*)(ws + (40ull << 20));    // 8 MB attn out

    // one cast launch: x + all 4 weights (wq/wk stacked into wqkb)
    cast_all<<<dim3(SEQ * DM / 1024, 2), dim3(256), 0, stream>>>(
        x, wq, wk, wv, wo, xb, wqkb, wvb, wob);

    // fused QK + V projections: 768 blocks, 32 KB LDS -> 4 blocks/CU
    gemm_qkv<<<dim3(768), dim3(256), 0, stream>>>(
        xb, wqkb, wvb, bq, bk, bv, QKb, Vtb);

    // attn: 1024 blocks, 27.6 KB LDS, (256,3) -> 3 blocks/CU
    attn_mfma<<<dim3(NH, 64), dim3(256), 0, stream>>>(QKb, QKb + 1024, Vtb, Ab);

    // out = attn@wo^T + bo (f32 out), BM=64 -> 512 blocks, 24 KB LDS
    gemm_o<<<dim3(DM / 128, SEQ / 64), dim3(256), 0, stream>>>(
        Ab, wob, bo, out);
}